// Round 1
// baseline (4976.748 us; speedup 1.0000x reference)
//
#include <hip/hip_runtime.h>
#include <hip/hip_bf16.h>

typedef unsigned short u16;
typedef __bf16 bf16x8 __attribute__((ext_vector_type(8)));
typedef float f32x4 __attribute__((ext_vector_type(4)));

#define NB 64
#define NT 128
#define NF 1024
#define NH 1024
#define NK 2048   // F+H
#define NG 4096   // 4H

__device__ __forceinline__ u16 f2bf(float f) {
  unsigned u = __builtin_bit_cast(unsigned, f);
  u = (u + 0x7FFFu + ((u >> 16) & 1u)) >> 16;
  return (u16)u;
}
__device__ __forceinline__ float bf2f(u16 v) {
  unsigned u = ((unsigned)v) << 16;
  return __builtin_bit_cast(float, u);
}

// ---------------- prep: x fp32 -> bf16 ----------------
__global__ __launch_bounds__(256) void lstm_cvt_x(const float* __restrict__ x,
                                                  u16* __restrict__ xb) {
  int i = (blockIdx.x * 256 + threadIdx.x) * 4;
  float4 v = *reinterpret_cast<const float4*>(x + i);
  ushort4 o;
  o.x = f2bf(v.x); o.y = f2bf(v.y); o.z = f2bf(v.z); o.w = f2bf(v.w);
  *reinterpret_cast<ushort4*>(xb + i) = o;
}

// ---------------- prep: W [2048,4096] fp32 -> Wt_hi/Wt_lo [4096,2048] bf16 ----------------
__global__ __launch_bounds__(256) void lstm_prep_w(const float* __restrict__ W,
                                                   u16* __restrict__ wt_hi,
                                                   u16* __restrict__ wt_lo) {
  __shared__ float tile[32][33];
  int n0 = blockIdx.x * 32;   // output row block (W column)
  int k0 = blockIdx.y * 32;   // output col block (W row)
  int tc = threadIdx.x & 31;
  int tr = threadIdx.x >> 5;  // 0..7
#pragma unroll
  for (int i = 0; i < 4; ++i) {
    int k = tr + i * 8;
    tile[k][tc] = W[(size_t)(k0 + k) * NG + n0 + tc];  // coalesced read
  }
  __syncthreads();
#pragma unroll
  for (int i = 0; i < 4; ++i) {
    int nn = tr + i * 8;                      // local n
    float w = tile[tc][nn];                   // = W[k0+tc][n0+nn]
    size_t off = (size_t)(n0 + nn) * NK + k0 + tc;  // coalesced in k
    u16 hi = f2bf(w);
    wt_hi[off] = hi;
    wt_lo[off] = f2bf(w - bf2f(hi));
  }
}

// ---------------- per-timestep fused GEMM + gates ----------------
// grid: (64, 2).  blockIdx.x -> 16 h-cols, blockIdx.y -> 32 batch-rows.
// wave w (0..3) computes gate w for the block's 32x16 tile over K=2048.
__global__ __launch_bounds__(256) void lstm_step(const u16* __restrict__ xb,
                                                 const u16* __restrict__ hin,
                                                 u16* __restrict__ hout,
                                                 const u16* __restrict__ wt_hi,
                                                 const u16* __restrict__ wt_lo,
                                                 const float* __restrict__ bias,
                                                 float* __restrict__ cbuf,
                                                 float* __restrict__ out,
                                                 int t) {
  const int c0 = blockIdx.x * 16;  // h-col base
  const int r0 = blockIdx.y * 32;  // batch-row base
  const int tid = threadIdx.x;
  const int wave = tid >> 6;       // = gate index
  const int lane = tid & 63;

  __shared__ u16 As[32][40];       // padded stride: 80 B (16-B aligned, ~2-way banks)
  __shared__ float zs[4][32][16];

  f32x4 acc0 = {0.f, 0.f, 0.f, 0.f};
  f32x4 acc1 = {0.f, 0.f, 0.f, 0.f};

  const size_t nrow = (size_t)(wave * NH + c0 + (lane & 15));
  const u16* bh = wt_hi + nrow * NK + 8 * (lane >> 4);
  const u16* bl = wt_lo + nrow * NK + 8 * (lane >> 4);

  const int ar = tid >> 3;         // 0..31 staged row
  const int ak = (tid & 7) * 4;    // 0..28 staged k offset (4 bf16 = 8 B)

  for (int k0 = 0; k0 < NK; k0 += 32) {
    __syncthreads();
    {
      const u16* asrc = (k0 < NF)
          ? xb + (((size_t)(r0 + ar) * NT + t) * NF + k0 + ak)
          : hin + ((size_t)(r0 + ar) * NH + (k0 - NF) + ak);
      *reinterpret_cast<uint2*>(&As[ar][ak]) = *reinterpret_cast<const uint2*>(asrc);
    }
    __syncthreads();
    bf16x8 a0 = *reinterpret_cast<const bf16x8*>(&As[lane & 15][8 * (lane >> 4)]);
    bf16x8 a1 = *reinterpret_cast<const bf16x8*>(&As[16 + (lane & 15)][8 * (lane >> 4)]);
    bf16x8 vh = *reinterpret_cast<const bf16x8*>(bh + k0);
    bf16x8 vl = *reinterpret_cast<const bf16x8*>(bl + k0);
    acc0 = __builtin_amdgcn_mfma_f32_16x16x32_bf16(a0, vh, acc0, 0, 0, 0);
    acc0 = __builtin_amdgcn_mfma_f32_16x16x32_bf16(a0, vl, acc0, 0, 0, 0);
    acc1 = __builtin_amdgcn_mfma_f32_16x16x32_bf16(a1, vh, acc1, 0, 0, 0);
    acc1 = __builtin_amdgcn_mfma_f32_16x16x32_bf16(a1, vl, acc1, 0, 0, 0);
  }

  // scatter z tiles to LDS: C/D layout col=lane&15, row=(lane>>4)*4+reg  [m89]
  {
    const int zc = lane & 15;
    const int zr = (lane >> 4) * 4;
#pragma unroll
    for (int r = 0; r < 4; ++r) {
      zs[wave][zr + r][zc] = acc0[r];
      zs[wave][16 + zr + r][zc] = acc1[r];
    }
  }
  __syncthreads();

  // fused gate pointwise: 32x16 elements, 2 per thread
#pragma unroll
  for (int e = tid; e < 512; e += 256) {
    const int row = e >> 4;
    const int col = e & 15;
    const int gr = r0 + row;
    const int gc = c0 + col;
    const float zi = zs[0][row][col] + bias[gc];
    const float zj = zs[1][row][col] + bias[NH + gc];
    const float zf = zs[2][row][col] + bias[2 * NH + gc];
    const float zo = zs[3][row][col] + bias[3 * NH + gc];
    const float cp = cbuf[gr * NH + gc];
    const float sf = 1.f / (1.f + __expf(-(zf + 1.0f)));  // FORGET_BIAS = 1
    const float si = 1.f / (1.f + __expf(-zi));
    const float so = 1.f / (1.f + __expf(-zo));
    const float cn = cp * sf + si * tanhf(zj);
    const float hn = tanhf(cn) * so;
    cbuf[gr * NH + gc] = cn;
    hout[gr * NH + gc] = f2bf(hn);
    out[((size_t)gr * NT + t) * NH + gc] = hn;
  }
}

extern "C" void kernel_launch(void* const* d_in, const int* in_sizes, int n_in,
                              void* d_out, int out_size, void* d_ws, size_t ws_size,
                              hipStream_t stream) {
  const float* x = (const float*)d_in[0];
  const float* W = (const float*)d_in[1];
  const float* bias = (const float*)d_in[2];
  float* out = (float*)d_out;

  char* ws = (char*)d_ws;
  u16* xb    = (u16*)(ws);                         // 16 MiB
  u16* wt_hi = (u16*)(ws + 16777216);              // 16 MiB
  u16* wt_lo = (u16*)(ws + 2 * 16777216);          // 16 MiB
  u16* hbuf  = (u16*)(ws + 3 * 16777216);          // 2 * 128 KiB ping-pong
  float* cbuf = (float*)(ws + 3 * 16777216 + 262144);  // 256 KiB

  hipMemsetAsync(cbuf, 0, NB * NH * sizeof(float), stream);
  hipMemsetAsync(hbuf, 0, 2 * NB * NH * sizeof(u16), stream);

  lstm_cvt_x<<<(NB * NT * NF) / (256 * 4), 256, 0, stream>>>(x, xb);
  lstm_prep_w<<<dim3(NG / 32, NK / 32), 256, 0, stream>>>(W, wt_hi, wt_lo);

  for (int t = 0; t < NT; ++t) {
    const u16* hin = hbuf + (t & 1) * (NB * NH);
    u16* hout = hbuf + ((t + 1) & 1) * (NB * NH);
    lstm_step<<<dim3(NH / 16, 2), 256, 0, stream>>>(xb, hin, hout, wt_hi, wt_lo,
                                                    bias, cbuf, out, t);
  }
}

// Round 2
// 3249.901 us; speedup vs baseline: 1.5314x; 1.5314x over previous
//
#include <hip/hip_runtime.h>
#include <hip/hip_bf16.h>

typedef unsigned short u16;
typedef __bf16 bf16x8 __attribute__((ext_vector_type(8)));
typedef float f32x4 __attribute__((ext_vector_type(4)));

#define NB 64
#define NT 128
#define NF 1024
#define NH 1024
#define NK 2048   // F+H
#define NG 4096   // 4H

__device__ __forceinline__ u16 f2bf(float f) {
  unsigned u = __builtin_bit_cast(unsigned, f);
  u = (u + 0x7FFFu + ((u >> 16) & 1u)) >> 16;
  return (u16)u;
}
__device__ __forceinline__ float bf2f(u16 v) {
  unsigned u = ((unsigned)v) << 16;
  return __builtin_bit_cast(float, u);
}

// ---------------- prep: x fp32 -> bf16 ----------------
__global__ __launch_bounds__(256) void lstm_cvt_x(const float* __restrict__ x,
                                                  u16* __restrict__ xb) {
  int i = (blockIdx.x * 256 + threadIdx.x) * 4;
  float4 v = *reinterpret_cast<const float4*>(x + i);
  ushort4 o;
  o.x = f2bf(v.x); o.y = f2bf(v.y); o.z = f2bf(v.z); o.w = f2bf(v.w);
  *reinterpret_cast<ushort4*>(xb + i) = o;
}

// ---------------- prep: W [2048,4096] fp32 -> block-sliced Wt hi/lo ----------------
// dest row for W column n (n = g*1024 + col):  drow = (col>>2)*16 + g*4 + (col&3)
// so block b's 16 rows (4 h-cols x 4 gates) are contiguous: 64 KB hi + 64 KB lo.
__global__ __launch_bounds__(256) void lstm_prep_w(const float* __restrict__ W,
                                                   u16* __restrict__ wt_hi,
                                                   u16* __restrict__ wt_lo) {
  __shared__ float tile[32][33];
  int n0 = blockIdx.x * 32;   // W column block
  int k0 = blockIdx.y * 32;   // W row block
  int tc = threadIdx.x & 31;
  int tr = threadIdx.x >> 5;  // 0..7
#pragma unroll
  for (int i = 0; i < 4; ++i) {
    int k = tr + i * 8;
    tile[k][tc] = W[(size_t)(k0 + k) * NG + n0 + tc];  // coalesced read
  }
  __syncthreads();
#pragma unroll
  for (int i = 0; i < 4; ++i) {
    int n = n0 + tr + i * 8;                  // global W column
    float w = tile[tc][tr + i * 8];           // = W[k0+tc][n]
    int g = n >> 10;
    int col = n & 1023;
    int drow = (col >> 2) * 16 + g * 4 + (col & 3);
    size_t off = (size_t)drow * NK + k0 + tc; // coalesced in k
    u16 hi = f2bf(w);
    wt_hi[off] = hi;
    wt_lo[off] = f2bf(w - bf2f(hi));
  }
}

// ---------------- per-timestep fused GEMM + gates ----------------
// grid: 256 blocks x 512 threads. Block b: h-cols [4b,4b+4) x 4 gates
// (W slice rows [16b,16b+16), contiguous 128 KB -> L2-resident per XCD).
// Waves: wid = (kh<<2)|msl : msl = M-slice of 16 batch rows, kh = K-half.
__global__ __launch_bounds__(512) void lstm_step(const u16* __restrict__ xb,
                                                 const u16* __restrict__ hin,
                                                 u16* __restrict__ hout,
                                                 const u16* __restrict__ wt_hi,
                                                 const u16* __restrict__ wt_lo,
                                                 const float* __restrict__ bias,
                                                 float* __restrict__ cbuf,
                                                 float* __restrict__ out,
                                                 int t) {
  const int tid = threadIdx.x;
  const int lane = tid & 63;
  const int wid = tid >> 6;
  const int msl = wid & 3;   // M slice (16 batch rows)
  const int kh = wid >> 2;   // K half (0: x, 1: h)

  __shared__ float zs[2][64][17];  // [K-half][batch row][nn], padded

  const int arow = msl * 16 + (lane & 15);
  const int kofs = 8 * (lane >> 4);

  const u16* ap = (kh == 0)
      ? xb + ((size_t)arow * NT + t) * NF + kofs
      : hin + (size_t)arow * NH + kofs;
  const int wrow = blockIdx.x * 16 + (lane & 15);
  const u16* wh = wt_hi + (size_t)wrow * NK + (size_t)kh * 1024 + kofs;
  const u16* wl = wt_lo + (size_t)wrow * NK + (size_t)kh * 1024 + kofs;

  f32x4 acc = {0.f, 0.f, 0.f, 0.f};
#pragma unroll 8
  for (int kk = 0; kk < 1024; kk += 32) {
    bf16x8 a  = *reinterpret_cast<const bf16x8*>(ap + kk);
    bf16x8 h8 = *reinterpret_cast<const bf16x8*>(wh + kk);
    bf16x8 l8 = *reinterpret_cast<const bf16x8*>(wl + kk);
    acc = __builtin_amdgcn_mfma_f32_16x16x32_bf16(a, h8, acc, 0, 0, 0);
    acc = __builtin_amdgcn_mfma_f32_16x16x32_bf16(a, l8, acc, 0, 0, 0);
  }

  // C/D layout: col = lane&15 (nn), row = (lane>>4)*4 + r (m within slice) [m89]
  {
    const int zr = msl * 16 + (lane >> 4) * 4;
    const int zc = lane & 15;
#pragma unroll
    for (int r = 0; r < 4; ++r) zs[kh][zr + r][zc] = acc[r];
  }
  __syncthreads();

  // pointwise: thread tid<64 owns batch row tid, the block's 4 h-cols
  if (tid < 64) {
    const int row = tid;
    const int gc0 = blockIdx.x * 4;
    float4 cv = *reinterpret_cast<const float4*>(cbuf + (size_t)row * NH + gc0);
    float hn[4];
    ushort4 hb;
#pragma unroll
    for (int j = 0; j < 4; ++j) {
      const int gc = gc0 + j;
      const float zi = zs[0][row][j]      + zs[1][row][j]      + bias[gc];
      const float zj = zs[0][row][4 + j]  + zs[1][row][4 + j]  + bias[NH + gc];
      const float zf = zs[0][row][8 + j]  + zs[1][row][8 + j]  + bias[2 * NH + gc];
      const float zo = zs[0][row][12 + j] + zs[1][row][12 + j] + bias[3 * NH + gc];
      const float sf = 1.f / (1.f + __expf(-(zf + 1.0f)));  // FORGET_BIAS = 1
      const float si = 1.f / (1.f + __expf(-zi));
      const float so = 1.f / (1.f + __expf(-zo));
      const float cn = ((float*)&cv)[j] * sf + si * tanhf(zj);
      const float h  = tanhf(cn) * so;
      ((float*)&cv)[j] = cn;
      hn[j] = h;
    }
    hb.x = f2bf(hn[0]); hb.y = f2bf(hn[1]); hb.z = f2bf(hn[2]); hb.w = f2bf(hn[3]);
    *reinterpret_cast<float4*>(cbuf + (size_t)row * NH + gc0) = cv;
    *reinterpret_cast<ushort4*>(hout + (size_t)row * NH + gc0) = hb;
    float4 ov = {hn[0], hn[1], hn[2], hn[3]};
    *reinterpret_cast<float4*>(out + ((size_t)row * NT + t) * NH + gc0) = ov;
  }
}

extern "C" void kernel_launch(void* const* d_in, const int* in_sizes, int n_in,
                              void* d_out, int out_size, void* d_ws, size_t ws_size,
                              hipStream_t stream) {
  const float* x = (const float*)d_in[0];
  const float* W = (const float*)d_in[1];
  const float* bias = (const float*)d_in[2];
  float* out = (float*)d_out;

  char* ws = (char*)d_ws;
  u16* xb    = (u16*)(ws);                         // 16 MiB
  u16* wt_hi = (u16*)(ws + 16777216);              // 16 MiB
  u16* wt_lo = (u16*)(ws + 2 * 16777216);          // 16 MiB
  u16* hbuf  = (u16*)(ws + 3 * 16777216);          // 2 * 128 KiB ping-pong
  float* cbuf = (float*)(ws + 3 * 16777216 + 262144);  // 256 KiB

  hipMemsetAsync(cbuf, 0, NB * NH * sizeof(float), stream);
  hipMemsetAsync(hbuf, 0, 2 * NB * NH * sizeof(u16), stream);

  lstm_cvt_x<<<(NB * NT * NF) / (256 * 4), 256, 0, stream>>>(x, xb);
  lstm_prep_w<<<dim3(NG / 32, NK / 32), 256, 0, stream>>>(W, wt_hi, wt_lo);

  for (int t = 0; t < NT; ++t) {
    const u16* hin = hbuf + (t & 1) * (NB * NH);
    u16* hout = hbuf + ((t + 1) & 1) * (NB * NH);
    lstm_step<<<256, 512, 0, stream>>>(xb, hin, hout, wt_hi, wt_lo,
                                       bias, cbuf, out, t);
  }
}

// Round 3
// 2718.069 us; speedup vs baseline: 1.8310x; 1.1957x over previous
//
#include <hip/hip_runtime.h>
#include <hip/hip_bf16.h>

typedef unsigned short u16;
typedef __bf16 bf16x8 __attribute__((ext_vector_type(8)));
typedef float f32x4 __attribute__((ext_vector_type(4)));

#define NB 64
#define NT 128
#define NF 1024
#define NH 1024
#define NK 2048   // F+H
#define NG 4096   // 4H
#define NBH (NB * NH)

// LDS: W slice 128 KiB + zs[4][64][17] f32
#define W_LDS_BYTES 131072
#define ZS_BYTES (4 * 64 * 17 * 4)
#define SMEM_BYTES (W_LDS_BYTES + ZS_BYTES)   // 148480 <= 163840

__device__ __forceinline__ u16 f2bf(float f) {
  unsigned u = __builtin_bit_cast(unsigned, f);
  u = (u + 0x7FFFu + ((u >> 16) & 1u)) >> 16;
  return (u16)u;
}
__device__ __forceinline__ float bf2f(u16 v) {
  unsigned u = ((unsigned)v) << 16;
  return __builtin_bit_cast(float, u);
}

// ---------------- prep: x fp32 -> bf16 ----------------
__global__ __launch_bounds__(256) void lstm_cvt_x(const float* __restrict__ x,
                                                  u16* __restrict__ xb) {
  int i = (blockIdx.x * 256 + threadIdx.x) * 4;
  float4 v = *reinterpret_cast<const float4*>(x + i);
  ushort4 o;
  o.x = f2bf(v.x); o.y = f2bf(v.y); o.z = f2bf(v.z); o.w = f2bf(v.w);
  *reinterpret_cast<ushort4*>(xb + i) = o;
}

// ---------------- prep: W [2048,4096] fp32 -> per-block LDS-image slices ----------------
// Block b owns W columns n = g*1024 + (b*4 + j), j=0..3, g=0..3 (brow = g*4+j).
// LDS image layout (u16 index within 65536-element block slice):
//   ((buf*2 + kh)*32 + ch)*512 + (slot*16 + brow)*8 + elem
// where k = kh*1024 + ch*32 + slot*8 + elem.  buf: 0=hi, 1=lo.
__global__ __launch_bounds__(256) void lstm_prep_w(const float* __restrict__ W,
                                                   u16* __restrict__ wt_blk) {
  __shared__ float tile[32][33];
  int n0 = blockIdx.x * 32;   // W column block
  int k0 = blockIdx.y * 32;   // W row block
  int tc = threadIdx.x & 31;
  int tr = threadIdx.x >> 5;  // 0..7
#pragma unroll
  for (int i = 0; i < 4; ++i) {
    int k = tr + i * 8;
    tile[k][tc] = W[(size_t)(k0 + k) * NG + n0 + tc];  // coalesced read
  }
  __syncthreads();
#pragma unroll
  for (int i = 0; i < 4; ++i) {
    int n = n0 + tr + i * 8;                  // global W column
    float wv = tile[tc][tr + i * 8];          // = W[k0+tc][n]
    int k = k0 + tc;
    int g = n >> 10, col = n & 1023;
    int b = col >> 2, brow = g * 4 + (col & 3);
    int kh = k >> 10, ch = (k & 1023) >> 5;
    int slot = (k >> 3) & 3, elem = k & 7;
    size_t base = (size_t)b * 65536 + (size_t)(kh * 32 + ch) * 512
                + (size_t)(slot * 16 + brow) * 8 + elem;
    u16 hi = f2bf(wv);
    wt_blk[base] = hi;                                   // buf 0 (hi)
    wt_blk[base + 32768] = f2bf(wv - bf2f(hi));          // buf 1 (lo)
  }
}

// ---------------- persistent LSTM: all 128 steps in one launch ----------------
// 256 blocks x 512 threads (8 waves). Wave w = K-slice of 256 (kh = w>>2 picks
// x vs h source). Each wave covers all M=64 rows (4 accs). W slice lives in LDS.
__global__ __launch_bounds__(512, 2) void lstm_persist(
    const u16* __restrict__ xb, u16* __restrict__ hbuf,
    const u16* __restrict__ wt_blk, const float* __restrict__ bias,
    float* __restrict__ out, unsigned int* __restrict__ flags) {
  extern __shared__ char smem[];
  u16* Wl = (u16*)smem;
  float (*zs)[64][17] = (float(*)[64][17])(smem + W_LDS_BYTES);

  const int b = blockIdx.x;
  const int tid = threadIdx.x;
  const int lane = tid & 63;
  const int w = tid >> 6;
  const int kq = w & 3;       // K-quarter within half
  const int kh = w >> 2;      // 0: x-half, 1: h-half

  // ---- load W slice (128 KiB) into LDS, linear copy ----
  {
    const u16* src = wt_blk + (size_t)b * 65536;
#pragma unroll
    for (int it = 0; it < 16; ++it) {
      uint4 v = *reinterpret_cast<const uint4*>(src + (size_t)it * 4096 + tid * 8);
      *reinterpret_cast<uint4*>(Wl + (size_t)it * 4096 + tid * 8) = v;
    }
  }

  const int arow = lane & 15;
  const int kfr = 8 * (lane >> 4);

  // pointwise ownership (fixed for all steps): thread tid<256 owns (prow, gc)
  const int prow = tid >> 2;
  const int pj = tid & 3;
  const int gc = b * 4 + pj;
  float bz0 = 0.f, bz1 = 0.f, bz2 = 0.f, bz3 = 0.f;
  float creg = 0.f;  // cell state lives in a register
  if (tid < 256) {
    bz0 = bias[gc];
    bz1 = bias[NH + gc];
    bz2 = bias[2 * NH + gc];
    bz3 = bias[3 * NH + gc];
  }
  __syncthreads();

#pragma unroll 1
  for (int t = 0; t < NT; ++t) {
    f32x4 acc[4] = {};
    const u16* hp = hbuf + (size_t)(t & 1) * NBH;
#pragma unroll
    for (int cc = 0; cc < 8; ++cc) {
      const int kloc = kq * 256 + cc * 32 + kfr;
      bf16x8 a[4];
      if (kh == 0) {
#pragma unroll
        for (int i = 0; i < 4; ++i)
          a[i] = *reinterpret_cast<const bf16x8*>(
              xb + ((size_t)(i * 16 + arow) * NT + t) * NF + kloc);
      } else {
#pragma unroll
        for (int i = 0; i < 4; ++i)
          a[i] = *reinterpret_cast<const bf16x8*>(
              hp + (size_t)(i * 16 + arow) * NH + kloc);
      }
      const int ch = kq * 8 + cc;
      const bf16x8 wh = *reinterpret_cast<const bf16x8*>(
          Wl + (size_t)(kh * 32 + ch) * 512 + lane * 8);
      const bf16x8 wl2 = *reinterpret_cast<const bf16x8*>(
          Wl + (size_t)((2 + kh) * 32 + ch) * 512 + lane * 8);
#pragma unroll
      for (int i = 0; i < 4; ++i)
        acc[i] = __builtin_amdgcn_mfma_f32_16x16x32_bf16(a[i], wh, acc[i], 0, 0, 0);
#pragma unroll
      for (int i = 0; i < 4; ++i)
        acc[i] = __builtin_amdgcn_mfma_f32_16x16x32_bf16(a[i], wl2, acc[i], 0, 0, 0);
    }

    // ---- 2-phase zs reduction over the 8 K-slice waves ----
    const int zn = lane & 15;
    const int mg = (lane >> 4) * 4;
    if (w < 4) {
#pragma unroll
      for (int i = 0; i < 4; ++i)
#pragma unroll
        for (int r = 0; r < 4; ++r) zs[w][i * 16 + mg + r][zn] = acc[i][r];
    }
    __syncthreads();
    if (w >= 4) {
#pragma unroll
      for (int i = 0; i < 4; ++i)
#pragma unroll
        for (int r = 0; r < 4; ++r) zs[w - 4][i * 16 + mg + r][zn] += acc[i][r];
    }
    __syncthreads();

    // ---- fused pointwise: 256 threads, one (row, col) each ----
    if (tid < 256) {
      const float zi = zs[0][prow][pj]      + zs[1][prow][pj]      + zs[2][prow][pj]      + zs[3][prow][pj]      + bz0;
      const float zj = zs[0][prow][4 + pj]  + zs[1][prow][4 + pj]  + zs[2][prow][4 + pj]  + zs[3][prow][4 + pj]  + bz1;
      const float zf = zs[0][prow][8 + pj]  + zs[1][prow][8 + pj]  + zs[2][prow][8 + pj]  + zs[3][prow][8 + pj]  + bz2;
      const float zo = zs[0][prow][12 + pj] + zs[1][prow][12 + pj] + zs[2][prow][12 + pj] + zs[3][prow][12 + pj] + bz3;
      const float si = 1.f / (1.f + __expf(-zi));
      const float tj = tanhf(zj);
      const float sf = 1.f / (1.f + __expf(-(zf + 1.0f)));  // FORGET_BIAS = 1
      const float so = 1.f / (1.f + __expf(-zo));
      const float cn = creg * sf + si * tj;
      const float hn = tanhf(cn) * so;
      creg = cn;
      hbuf[(size_t)((t + 1) & 1) * NBH + prow * NH + gc] = f2bf(hn);
      out[((size_t)prow * NT + t) * NH + gc] = hn;
    }

    // ---- device-scope grid barrier (per-step flag array) ----
    __syncthreads();  // drains this block's h stores to its L2 (vmcnt 0)
    if (w == 0) {
      if (lane == 0)
        __hip_atomic_store(&flags[(size_t)t * 256 + b], 1u,
                           __ATOMIC_RELEASE, __HIP_MEMORY_SCOPE_AGENT);
      const unsigned* fb = flags + (size_t)t * 256 + lane * 4;
      bool ok;
      do {
        unsigned v0 = __hip_atomic_load(fb + 0, __ATOMIC_RELAXED, __HIP_MEMORY_SCOPE_AGENT);
        unsigned v1 = __hip_atomic_load(fb + 1, __ATOMIC_RELAXED, __HIP_MEMORY_SCOPE_AGENT);
        unsigned v2 = __hip_atomic_load(fb + 2, __ATOMIC_RELAXED, __HIP_MEMORY_SCOPE_AGENT);
        unsigned v3 = __hip_atomic_load(fb + 3, __ATOMIC_RELAXED, __HIP_MEMORY_SCOPE_AGENT);
        ok = ((v0 & v1 & v2 & v3) == 1u);
      } while (!__all(ok));
      (void)__hip_atomic_load(fb, __ATOMIC_ACQUIRE, __HIP_MEMORY_SCOPE_AGENT);
    }
    __syncthreads();
  }
}

extern "C" void kernel_launch(void* const* d_in, const int* in_sizes, int n_in,
                              void* d_out, int out_size, void* d_ws, size_t ws_size,
                              hipStream_t stream) {
  const float* x = (const float*)d_in[0];
  const float* W = (const float*)d_in[1];
  const float* bias = (const float*)d_in[2];
  float* out = (float*)d_out;

  char* ws = (char*)d_ws;
  u16* xb = (u16*)(ws);                                   // 16 MiB
  u16* wt_blk = (u16*)(ws + 16777216);                    // 32 MiB
  u16* hbuf = (u16*)(ws + 50331648);                      // 256 KiB ping-pong
  unsigned int* flags = (unsigned int*)(ws + 50331648 + 262144);  // 128 KiB

  hipMemsetAsync(hbuf, 0, 2 * NBH * sizeof(u16), stream);
  hipMemsetAsync(flags, 0, NT * 256 * sizeof(unsigned int), stream);

  lstm_cvt_x<<<(NB * NT * NF) / (256 * 4), 256, 0, stream>>>(x, xb);
  lstm_prep_w<<<dim3(NG / 32, NK / 32), 256, 0, stream>>>(W, wt_blk);

  static int attr_done = 0;
  (void)attr_done;
  hipFuncSetAttribute((const void*)lstm_persist,
                      hipFuncAttributeMaxDynamicSharedMemorySize, SMEM_BYTES);

  void* args[] = {(void*)&xb, (void*)&hbuf, (void*)&wt_blk, (void*)&bias,
                  (void*)&out, (void*)&flags};
  hipLaunchCooperativeKernel((void*)lstm_persist, dim3(256), dim3(512), args,
                             SMEM_BYTES, stream);
}

// Round 4
// 2177.800 us; speedup vs baseline: 2.2852x; 1.2481x over previous
//
#include <hip/hip_runtime.h>
#include <hip/hip_bf16.h>

typedef unsigned short u16;
typedef unsigned int u32;
typedef __bf16 bf16x8 __attribute__((ext_vector_type(8)));
typedef float f32x4 __attribute__((ext_vector_type(4)));

#define NB 64
#define NT 128
#define NF 1024
#define NH 1024
#define NK 2048   // F+H
#define NG 4096   // 4H
#define NBH (NB * NH)

// LDS: W slice 128 KiB + zs[4][64][17] f32
#define W_LDS_BYTES 131072
#define ZS_BYTES (4 * 64 * 17 * 4)
#define SMEM_BYTES (W_LDS_BYTES + ZS_BYTES)   // 148480 <= 163840

__device__ __forceinline__ u16 f2bf(float f) {
  unsigned u = __builtin_bit_cast(unsigned, f);
  u = (u + 0x7FFFu + ((u >> 16) & 1u)) >> 16;
  return (u16)u;
}
__device__ __forceinline__ float bf2f(u16 v) {
  unsigned u = ((unsigned)v) << 16;
  return __builtin_bit_cast(float, u);
}
__device__ __forceinline__ bf16x8 cvt8(float4 a, float4 b) {
  bf16x8 r;
  r[0] = (__bf16)a.x; r[1] = (__bf16)a.y; r[2] = (__bf16)a.z; r[3] = (__bf16)a.w;
  r[4] = (__bf16)b.x; r[5] = (__bf16)b.y; r[6] = (__bf16)b.z; r[7] = (__bf16)b.w;
  return r;
}

// ---------------- prep: W [2048,4096] fp32 -> per-block LDS-image slices ----------------
// Block b owns W columns n = g*1024 + (b*4 + j), j=0..3, g=0..3 (brow = g*4+j).
// LDS image (u16 index within 65536-elem slice):
//   ((buf*2 + kh)*32 + ch)*512 + (slot*16 + brow)*8 + elem,  k = kh*1024+ch*32+slot*8+elem
__global__ __launch_bounds__(256) void lstm_prep_w(const float* __restrict__ W,
                                                   u16* __restrict__ wt_blk) {
  __shared__ float tile[32][33];
  int n0 = blockIdx.x * 32;   // W column block
  int k0 = blockIdx.y * 32;   // W row block
  int tc = threadIdx.x & 31;
  int tr = threadIdx.x >> 5;  // 0..7
#pragma unroll
  for (int i = 0; i < 4; ++i) {
    int k = tr + i * 8;
    tile[k][tc] = W[(size_t)(k0 + k) * NG + n0 + tc];  // coalesced read
  }
  __syncthreads();
#pragma unroll
  for (int i = 0; i < 4; ++i) {
    int n = n0 + tr + i * 8;                  // global W column
    float wv = tile[tc][tr + i * 8];          // = W[k0+tc][n]
    int k = k0 + tc;
    int g = n >> 10, col = n & 1023;
    int b = col >> 2, brow = g * 4 + (col & 3);
    int kh = k >> 10, ch = (k & 1023) >> 5;
    int slot = (k >> 3) & 3, elem = k & 7;
    size_t base = (size_t)b * 65536 + (size_t)(kh * 32 + ch) * 512
                + (size_t)(slot * 16 + brow) * 8 + elem;
    u16 hi = f2bf(wv);
    wt_blk[base] = hi;                                   // buf 0 (hi)
    wt_blk[base + 32768] = f2bf(wv - bf2f(hi));          // buf 1 (lo)
  }
}

// ---------------- persistent LSTM: all 128 steps in one launch ----------------
// 256 blocks x 512 threads (8 waves). Wave w: kq = w&3 (K-quarter), kh = w>>2
// (0 = x half in fp32->bf16 on the fly, 1 = h half from per-step fresh buffer).
// Grid barrier: h written via agent-scope relaxed atomic stores (sc1 -> LLC),
// vmcnt(0), relaxed flag store; pollers use relaxed agent loads. NO
// release/acquire fences -> no buffer_wbl2 / buffer_inv -> x stays L2-resident.
// Freshness: hseq[t+1] lines were never cached by any reader before this step.
__global__ __launch_bounds__(512) void lstm_persist(
    const float* __restrict__ x, u16* __restrict__ hseq,
    const u16* __restrict__ wt_blk, const float* __restrict__ bias,
    float* __restrict__ out, u32* __restrict__ flags) {
  extern __shared__ char smem[];
  u16* Wl = (u16*)smem;
  float (*zs)[64][17] = (float(*)[64][17])(smem + W_LDS_BYTES);

  const int b = blockIdx.x;
  const int tid = threadIdx.x;
  const int lane = tid & 63;
  const int w = tid >> 6;
  const int kq = w & 3;       // K-quarter within half
  const int kh = w >> 2;      // 0: x-half, 1: h-half

  // ---- load W slice (128 KiB) into LDS ----
  {
    const u16* src = wt_blk + (size_t)b * 65536;
#pragma unroll
    for (int it = 0; it < 16; ++it) {
      uint4 v = *reinterpret_cast<const uint4*>(src + (size_t)it * 4096 + tid * 8);
      *reinterpret_cast<uint4*>(Wl + (size_t)it * 4096 + tid * 8) = v;
    }
  }

  const int arow = lane & 15;
  const int kfr = 8 * (lane >> 4);
  const int kbase = kq * 256 + kfr;

  // pointwise ownership (fixed for all steps): tid<128 owns (prow, 2 cols)
  const int prow = tid >> 1;
  const int pc = (tid & 1) * 2;
  const int gc0 = b * 4 + pc;
  float bz[2][4];
  float creg[2] = {0.f, 0.f};
  if (tid < 128) {
#pragma unroll
    for (int j = 0; j < 2; ++j) {
      bz[j][0] = bias[gc0 + j];
      bz[j][1] = bias[NH + gc0 + j];
      bz[j][2] = bias[2 * NH + gc0 + j];
      bz[j][3] = bias[3 * NH + gc0 + j];
    }
  }
  __syncthreads();

#pragma unroll 1
  for (int t = 0; t < NT; ++t) {
    f32x4 acc[4] = {};

    if (kh == 0) {
      // ---- x half: fp32 loads, cvt to bf16, 2-stage pipeline ----
      const float* xr[4];
#pragma unroll
      for (int i = 0; i < 4; ++i)
        xr[i] = x + ((size_t)(i * 16 + arow) * NT + t) * NF + kbase;
      float4 pa[4], pb[4], qa[4], qb[4];
#pragma unroll
      for (int i = 0; i < 4; ++i) {
        pa[i] = *reinterpret_cast<const float4*>(xr[i]);
        pb[i] = *reinterpret_cast<const float4*>(xr[i] + 4);
      }
#pragma unroll
      for (int cc = 0; cc < 8; ++cc) {
        if (cc < 7) {
#pragma unroll
          for (int i = 0; i < 4; ++i) {
            qa[i] = *reinterpret_cast<const float4*>(xr[i] + (cc + 1) * 32);
            qb[i] = *reinterpret_cast<const float4*>(xr[i] + (cc + 1) * 32 + 4);
          }
        }
        const int ch = kq * 8 + cc;
        const bf16x8 wh = *reinterpret_cast<const bf16x8*>(
            Wl + (size_t)(ch) * 512 + lane * 8);                    // kh=0 hi
        const bf16x8 wlo = *reinterpret_cast<const bf16x8*>(
            Wl + (size_t)(64 + ch) * 512 + lane * 8);               // kh=0 lo
#pragma unroll
        for (int i = 0; i < 4; ++i) {
          bf16x8 a = cvt8(pa[i], pb[i]);
          acc[i] = __builtin_amdgcn_mfma_f32_16x16x32_bf16(a, wh, acc[i], 0, 0, 0);
          acc[i] = __builtin_amdgcn_mfma_f32_16x16x32_bf16(a, wlo, acc[i], 0, 0, 0);
        }
#pragma unroll
        for (int i = 0; i < 4; ++i) { pa[i] = qa[i]; pb[i] = qb[i]; }
      }
    } else {
      // ---- h half: bf16 loads from fresh per-step buffer, 2-stage pipeline ----
      const u16* hr[4];
#pragma unroll
      for (int i = 0; i < 4; ++i)
        hr[i] = hseq + (size_t)t * NBH + (size_t)(i * 16 + arow) * NH + kbase;
      bf16x8 pf[4], qf[4];
#pragma unroll
      for (int i = 0; i < 4; ++i)
        pf[i] = *reinterpret_cast<const bf16x8*>(hr[i]);
#pragma unroll
      for (int cc = 0; cc < 8; ++cc) {
        if (cc < 7) {
#pragma unroll
          for (int i = 0; i < 4; ++i)
            qf[i] = *reinterpret_cast<const bf16x8*>(hr[i] + (cc + 1) * 32);
        }
        const int ch = kq * 8 + cc;
        const bf16x8 wh = *reinterpret_cast<const bf16x8*>(
            Wl + (size_t)(32 + ch) * 512 + lane * 8);               // kh=1 hi
        const bf16x8 wlo = *reinterpret_cast<const bf16x8*>(
            Wl + (size_t)(96 + ch) * 512 + lane * 8);               // kh=1 lo
#pragma unroll
        for (int i = 0; i < 4; ++i) {
          acc[i] = __builtin_amdgcn_mfma_f32_16x16x32_bf16(pf[i], wh, acc[i], 0, 0, 0);
          acc[i] = __builtin_amdgcn_mfma_f32_16x16x32_bf16(pf[i], wlo, acc[i], 0, 0, 0);
        }
#pragma unroll
        for (int i = 0; i < 4; ++i) pf[i] = qf[i];
      }
    }

    // ---- 2-phase zs reduction over the 8 K-slice waves ----
    const int zn = lane & 15;
    const int mg = (lane >> 4) * 4;
    if (w < 4) {
#pragma unroll
      for (int i = 0; i < 4; ++i)
#pragma unroll
        for (int r = 0; r < 4; ++r) zs[w][i * 16 + mg + r][zn] = acc[i][r];
    }
    __syncthreads();
    if (w >= 4) {
#pragma unroll
      for (int i = 0; i < 4; ++i)
#pragma unroll
        for (int r = 0; r < 4; ++r) zs[w - 4][i * 16 + mg + r][zn] += acc[i][r];
    }
    __syncthreads();

    // ---- fused pointwise: 128 threads, (row, 2 cols) each ----
    if (tid < 128) {
      float hn[2];
#pragma unroll
      for (int j = 0; j < 2; ++j) {
        const int col = pc + j;
        const float zi = zs[0][prow][col]      + zs[1][prow][col]      + zs[2][prow][col]      + zs[3][prow][col]      + bz[j][0];
        const float zj = zs[0][prow][4 + col]  + zs[1][prow][4 + col]  + zs[2][prow][4 + col]  + zs[3][prow][4 + col]  + bz[j][1];
        const float zf = zs[0][prow][8 + col]  + zs[1][prow][8 + col]  + zs[2][prow][8 + col]  + zs[3][prow][8 + col]  + bz[j][2];
        const float zo = zs[0][prow][12 + col] + zs[1][prow][12 + col] + zs[2][prow][12 + col] + zs[3][prow][12 + col] + bz[j][3];
        const float si = 1.f / (1.f + __expf(-zi));
        const float tj = tanhf(zj);
        const float sf = 1.f / (1.f + __expf(-(zf + 1.0f)));  // FORGET_BIAS = 1
        const float so = 1.f / (1.f + __expf(-zo));
        const float cn = creg[j] * sf + si * tj;
        hn[j] = tanhf(cn) * so;
        creg[j] = cn;
      }
      // out: plain fp32 store (flushed at kernel end)
      float2 ov = {hn[0], hn[1]};
      *reinterpret_cast<float2*>(out + ((size_t)prow * NT + t) * NH + gc0) = ov;
      // h: write-through to LLC (agent-scope relaxed atomic -> sc1, no wbl2)
      u32 hv = (u32)f2bf(hn[0]) | ((u32)f2bf(hn[1]) << 16);
      __hip_atomic_store(
          reinterpret_cast<u32*>(hseq + (size_t)(t + 1) * NBH + (size_t)prow * NH + gc0),
          hv, __ATOMIC_RELAXED, __HIP_MEMORY_SCOPE_AGENT);
    }

    if (t == NT - 1) break;  // no barrier needed after last step

    // ---- flush-free grid barrier ----
    asm volatile("s_waitcnt vmcnt(0)" ::: "memory");  // h stores acked at LLC
    __syncthreads();
    if (w == 0) {
      if (lane == 0)
        __hip_atomic_store(&flags[(size_t)t * 256 + b], 1u,
                           __ATOMIC_RELAXED, __HIP_MEMORY_SCOPE_AGENT);
      const u32* fb = flags + (size_t)t * 256 + lane * 4;
      bool ok;
      do {
        u32 v0 = __hip_atomic_load(fb + 0, __ATOMIC_RELAXED, __HIP_MEMORY_SCOPE_AGENT);
        u32 v1 = __hip_atomic_load(fb + 1, __ATOMIC_RELAXED, __HIP_MEMORY_SCOPE_AGENT);
        u32 v2 = __hip_atomic_load(fb + 2, __ATOMIC_RELAXED, __HIP_MEMORY_SCOPE_AGENT);
        u32 v3 = __hip_atomic_load(fb + 3, __ATOMIC_RELAXED, __HIP_MEMORY_SCOPE_AGENT);
        ok = ((v0 & v1 & v2 & v3) == 1u);
      } while (!__all(ok));
      asm volatile("" ::: "memory");
    }
    __syncthreads();
  }
}

extern "C" void kernel_launch(void* const* d_in, const int* in_sizes, int n_in,
                              void* d_out, int out_size, void* d_ws, size_t ws_size,
                              hipStream_t stream) {
  const float* x = (const float*)d_in[0];
  const float* W = (const float*)d_in[1];
  const float* bias = (const float*)d_in[2];
  float* out = (float*)d_out;

  char* ws = (char*)d_ws;
  u16* hseq = (u16*)(ws);                              // 129 * 128 KiB = 16.125 MiB
  u16* wt_blk = (u16*)(ws + 16908288);                 // 32 MiB
  u32* flags = (u32*)(ws + 16908288 + 33554432);       // 128 KiB  (total ~50.6 MiB)

  hipMemsetAsync(hseq, 0, NBH * sizeof(u16), stream);                 // h_0 = 0
  hipMemsetAsync(flags, 0, NT * 256 * sizeof(u32), stream);           // per-replay

  lstm_prep_w<<<dim3(NG / 32, NK / 32), 256, 0, stream>>>(W, wt_blk);

  hipFuncSetAttribute((const void*)lstm_persist,
                      hipFuncAttributeMaxDynamicSharedMemorySize, SMEM_BYTES);

  void* args[] = {(void*)&x, (void*)&hseq, (void*)&wt_blk, (void*)&bias,
                  (void*)&out, (void*)&flags};
  hipLaunchCooperativeKernel((void*)lstm_persist, dim3(256), dim3(512), args,
                             SMEM_BYTES, stream);
}

// Round 5
// 1529.750 us; speedup vs baseline: 3.2533x; 1.4236x over previous
//
#include <hip/hip_runtime.h>
#include <hip/hip_bf16.h>

typedef unsigned short u16;
typedef unsigned int u32;
typedef __bf16 bf16x8 __attribute__((ext_vector_type(8)));
typedef float f32x4 __attribute__((ext_vector_type(4)));

#define NB 64
#define NT 128
#define NF 1024
#define NH 1024
#define NK 2048   // F+H
#define NG 4096   // 4H
#define NBH (NB * NH)

// LDS: W slice 128 KiB + zsx[2 buf][2][64][17] + zsh[2][64][17]
#define W_LDS_BYTES 131072
#define ZSX_BYTES (2 * 2 * 64 * 17 * 4)   // 17408
#define ZSH_BYTES (2 * 64 * 17 * 4)       // 8704
#define SMEM_BYTES (W_LDS_BYTES + ZSX_BYTES + ZSH_BYTES)  // 157184 <= 163840

__device__ __forceinline__ u16 f2bf(float f) {
  unsigned u = __builtin_bit_cast(unsigned, f);
  u = (u + 0x7FFFu + ((u >> 16) & 1u)) >> 16;
  return (u16)u;
}
__device__ __forceinline__ float bf2f(u16 v) {
  unsigned u = ((unsigned)v) << 16;
  return __builtin_bit_cast(float, u);
}

// ---------------- prep: x fp32 -> bf16 ----------------
__global__ __launch_bounds__(256) void lstm_cvt_x(const float* __restrict__ x,
                                                  u16* __restrict__ xb) {
  int i = (blockIdx.x * 256 + threadIdx.x) * 4;
  float4 v = *reinterpret_cast<const float4*>(x + i);
  ushort4 o;
  o.x = f2bf(v.x); o.y = f2bf(v.y); o.z = f2bf(v.z); o.w = f2bf(v.w);
  *reinterpret_cast<ushort4*>(xb + i) = o;
}

// ---------------- prep: W [2048,4096] fp32 -> per-block LDS-image slices ----------------
// (unchanged from R3/R4 - verified)
__global__ __launch_bounds__(256) void lstm_prep_w(const float* __restrict__ W,
                                                   u16* __restrict__ wt_blk) {
  __shared__ float tile[32][33];
  int n0 = blockIdx.x * 32;
  int k0 = blockIdx.y * 32;
  int tc = threadIdx.x & 31;
  int tr = threadIdx.x >> 5;
#pragma unroll
  for (int i = 0; i < 4; ++i) {
    int k = tr + i * 8;
    tile[k][tc] = W[(size_t)(k0 + k) * NG + n0 + tc];
  }
  __syncthreads();
#pragma unroll
  for (int i = 0; i < 4; ++i) {
    int n = n0 + tr + i * 8;
    float wv = tile[tc][tr + i * 8];
    int k = k0 + tc;
    int g = n >> 10, col = n & 1023;
    int b = col >> 2, brow = g * 4 + (col & 3);
    int kh = k >> 10, ch = (k & 1023) >> 5;
    int slot = (k >> 3) & 3, elem = k & 7;
    size_t base = (size_t)b * 65536 + (size_t)(kh * 32 + ch) * 512
                + (size_t)(slot * 16 + brow) * 8 + elem;
    u16 hi = f2bf(wv);
    wt_blk[base] = hi;
    wt_blk[base + 32768] = f2bf(wv - bf2f(hi));
  }
}

// A-pass: 4 M-frags (rows i*16+arow), K=256 slice, hi+lo MFMA, 2-stage pipeline.
__device__ __forceinline__ void mfma_pass(const u16* __restrict__ a0, size_t rstride,
                                          const u16* __restrict__ Wl, int khalf,
                                          int kq, int lane, f32x4 acc[4]) {
  bf16x8 pf[4], qf[4];
#pragma unroll
  for (int i = 0; i < 4; ++i)
    pf[i] = *reinterpret_cast<const bf16x8*>(a0 + (size_t)i * 16 * rstride);
#pragma unroll
  for (int cc = 0; cc < 8; ++cc) {
    if (cc < 7) {
#pragma unroll
      for (int i = 0; i < 4; ++i)
        qf[i] = *reinterpret_cast<const bf16x8*>(a0 + (size_t)i * 16 * rstride + (cc + 1) * 32);
    }
    const int ch = kq * 8 + cc;
    const bf16x8 wh = *reinterpret_cast<const bf16x8*>(
        Wl + (size_t)(khalf * 32 + ch) * 512 + lane * 8);
    const bf16x8 wl2 = *reinterpret_cast<const bf16x8*>(
        Wl + (size_t)(64 + khalf * 32 + ch) * 512 + lane * 8);
#pragma unroll
    for (int i = 0; i < 4; ++i)
      acc[i] = __builtin_amdgcn_mfma_f32_16x16x32_bf16(pf[i], wh, acc[i], 0, 0, 0);
#pragma unroll
    for (int i = 0; i < 4; ++i)
      acc[i] = __builtin_amdgcn_mfma_f32_16x16x32_bf16(pf[i], wl2, acc[i], 0, 0, 0);
#pragma unroll
    for (int i = 0; i < 4; ++i) pf[i] = qf[i];
  }
}

// ---------------- persistent LSTM, dataflow-synced ----------------
// 256 blocks x 512 threads. Waves 0-3: x-GEMM for step t+1 (no inter-block
// deps, run 1 step ahead into zsx double buffer). Waves 4-7: h-GEMM for step
// t; wave kq polls only its 64 producer blocks' flags (h-cols 256kq..+256 are
// produced by blocks 64kq..64kq+64). No full grid barrier.
__global__ __launch_bounds__(512) void lstm_persist(
    const u16* __restrict__ xb, u16* __restrict__ hseq,
    const u16* __restrict__ wt_blk, const float* __restrict__ bias,
    float* __restrict__ out, u32* __restrict__ flags) {
  extern __shared__ char smem[];
  u16* Wl = (u16*)smem;
  float (*zsx)[2][64][17] = (float(*)[2][64][17])(smem + W_LDS_BYTES);
  float (*zsh)[64][17] = (float(*)[64][17])(smem + W_LDS_BYTES + ZSX_BYTES);

  const int b = blockIdx.x;
  const int tid = threadIdx.x;
  const int lane = tid & 63;
  const int w = tid >> 6;
  const bool is_x = (w < 4);
  const int kq = w & 3;

  // ---- load W slice (128 KiB) into LDS ----
  {
    const u16* src = wt_blk + (size_t)b * 65536;
#pragma unroll
    for (int it = 0; it < 16; ++it) {
      uint4 v = *reinterpret_cast<const uint4*>(src + (size_t)it * 4096 + tid * 8);
      *reinterpret_cast<uint4*>(Wl + (size_t)it * 4096 + tid * 8) = v;
    }
  }
  // zero zsh (t=0 has no h contribution)
  for (int i = tid; i < 2 * 64 * 17; i += 512) ((float*)zsh)[i] = 0.f;

  const int arow = lane & 15;
  const int kfr = 8 * (lane >> 4);
  const int kbase = kq * 256 + kfr;
  const int zn = lane & 15;
  const int mg = (lane >> 4) * 4;

  // pointwise ownership: tid<128 owns (prow, 2 cols)
  const int prow = tid >> 1;
  const int pc = (tid & 1) * 2;
  const int gc0 = b * 4 + pc;
  float bz[2][4];
  float creg[2] = {0.f, 0.f};
  if (tid < 128) {
#pragma unroll
    for (int j = 0; j < 2; ++j) {
      bz[j][0] = bias[gc0 + j];
      bz[j][1] = bias[NH + gc0 + j];
      bz[j][2] = bias[2 * NH + gc0 + j];
      bz[j][3] = bias[3 * NH + gc0 + j];
    }
  }
  __syncthreads();

  // ---- prologue: x-waves fill zsx[0] = zx(0) ----
  {
    f32x4 acc[4] = {};
    if (is_x) {
      const u16* a0 = xb + ((size_t)arow * NT + 0) * NF + kbase;
      mfma_pass(a0, (size_t)NT * NF, Wl, 0, kq, lane, acc);
      if (w < 2) {
#pragma unroll
        for (int i = 0; i < 4; ++i)
#pragma unroll
          for (int r = 0; r < 4; ++r) zsx[0][w][i * 16 + mg + r][zn] = acc[i][r];
      }
    }
    __syncthreads();
    if (is_x && w >= 2) {
#pragma unroll
      for (int i = 0; i < 4; ++i)
#pragma unroll
        for (int r = 0; r < 4; ++r) zsx[0][w - 2][i * 16 + mg + r][zn] += acc[i][r];
    }
    __syncthreads();
  }

#pragma unroll 1
  for (int t = 0; t < NT; ++t) {
    const int cb = t & 1;        // zsx buffer consumed this step
    const int nb = (t + 1) & 1;  // zsx buffer filled this step
    f32x4 acc[4] = {};

    if (is_x) {
      if (t < NT - 1) {
        const u16* a0 = xb + ((size_t)arow * NT + (t + 1)) * NF + kbase;
        mfma_pass(a0, (size_t)NT * NF, Wl, 0, kq, lane, acc);
      }
    } else {
      if (t > 0) {
        // dataflow poll: only this wave's 64 producer blocks
        const u32* fp = flags + (size_t)t * 256 + kq * 64 + lane;
        u32 v;
        do {
          v = __hip_atomic_load(fp, __ATOMIC_RELAXED, __HIP_MEMORY_SCOPE_AGENT);
        } while (!__all(v != 0));
        const u16* a0 = hseq + (size_t)t * NBH + (size_t)arow * NH + kbase;
        __builtin_amdgcn_s_setprio(1);
        mfma_pass(a0, (size_t)NH, Wl, 1, kq, lane, acc);
        __builtin_amdgcn_s_setprio(0);
      }
    }

    // ---- write phase ----
    if (is_x) {
      if (w < 2 && t < NT - 1) {
#pragma unroll
        for (int i = 0; i < 4; ++i)
#pragma unroll
          for (int r = 0; r < 4; ++r) zsx[nb][w][i * 16 + mg + r][zn] = acc[i][r];
      }
    } else {
      if (w < 6 && t > 0) {
#pragma unroll
        for (int i = 0; i < 4; ++i)
#pragma unroll
          for (int r = 0; r < 4; ++r) zsh[w - 4][i * 16 + mg + r][zn] = acc[i][r];
      }
    }
    __syncthreads();
    // ---- add phase ----
    if (is_x) {
      if (w >= 2 && t < NT - 1) {
#pragma unroll
        for (int i = 0; i < 4; ++i)
#pragma unroll
          for (int r = 0; r < 4; ++r) zsx[nb][w - 2][i * 16 + mg + r][zn] += acc[i][r];
      }
    } else {
      if (w >= 6 && t > 0) {
#pragma unroll
        for (int i = 0; i < 4; ++i)
#pragma unroll
          for (int r = 0; r < 4; ++r) zsh[w - 6][i * 16 + mg + r][zn] += acc[i][r];
      }
    }
    __syncthreads();

    // ---- fused pointwise: 128 threads, (row, 2 cols) each ----
    if (tid < 128) {
      float hn[2];
#pragma unroll
      for (int j = 0; j < 2; ++j) {
        const int col = pc + j;
        const float zi = zsx[cb][0][prow][col]      + zsx[cb][1][prow][col]      + zsh[0][prow][col]      + zsh[1][prow][col]      + bz[j][0];
        const float zj = zsx[cb][0][prow][4 + col]  + zsx[cb][1][prow][4 + col]  + zsh[0][prow][4 + col]  + zsh[1][prow][4 + col]  + bz[j][1];
        const float zf = zsx[cb][0][prow][8 + col]  + zsx[cb][1][prow][8 + col]  + zsh[0][prow][8 + col]  + zsh[1][prow][8 + col]  + bz[j][2];
        const float zo = zsx[cb][0][prow][12 + col] + zsx[cb][1][prow][12 + col] + zsh[0][prow][12 + col] + zsh[1][prow][12 + col] + bz[j][3];
        const float si = 1.f / (1.f + __expf(-zi));
        const float tj = tanhf(zj);
        const float sf = 1.f / (1.f + __expf(-(zf + 1.0f)));  // FORGET_BIAS = 1
        const float so = 1.f / (1.f + __expf(-zo));
        const float cn = creg[j] * sf + si * tj;
        hn[j] = tanhf(cn) * so;
        creg[j] = cn;
      }
      float2 ov = {hn[0], hn[1]};
      *reinterpret_cast<float2*>(out + ((size_t)prow * NT + t) * NH + gc0) = ov;
      if (t < NT - 1) {
        u32 hv = (u32)f2bf(hn[0]) | ((u32)f2bf(hn[1]) << 16);
        __hip_atomic_store(
            reinterpret_cast<u32*>(hseq + (size_t)(t + 1) * NBH + (size_t)prow * NH + gc0),
            hv, __ATOMIC_RELAXED, __HIP_MEMORY_SCOPE_AGENT);
        asm volatile("s_waitcnt vmcnt(0)" ::: "memory");  // h acked at LLC
      }
    }
    __syncthreads();
    if (tid == 0 && t < NT - 1)
      __hip_atomic_store(&flags[(size_t)(t + 1) * 256 + b], 1u,
                         __ATOMIC_RELAXED, __HIP_MEMORY_SCOPE_AGENT);
  }
}

extern "C" void kernel_launch(void* const* d_in, const int* in_sizes, int n_in,
                              void* d_out, int out_size, void* d_ws, size_t ws_size,
                              hipStream_t stream) {
  const float* x = (const float*)d_in[0];
  const float* W = (const float*)d_in[1];
  const float* bias = (const float*)d_in[2];
  float* out = (float*)d_out;

  char* ws = (char*)d_ws;
  u16* xb = (u16*)(ws);                                  // 16 MiB
  u16* wt_blk = (u16*)(ws + 16777216);                   // 32 MiB
  u16* hseq = (u16*)(ws + 50331648);                     // 128 * 128 KiB = 16 MiB
  u32* flags = (u32*)(ws + 50331648 + 16777216);         // 128 KiB (total ~64.1 MiB)

  hipMemsetAsync(hseq, 0, NBH * sizeof(u16), stream);            // h_0 = 0
  hipMemsetAsync(flags, 0, NT * 256 * sizeof(u32), stream);      // per-replay

  lstm_cvt_x<<<(NB * NT * NF) / (256 * 4), 256, 0, stream>>>(x, xb);
  lstm_prep_w<<<dim3(NG / 32, NK / 32), 256, 0, stream>>>(W, wt_blk);

  hipFuncSetAttribute((const void*)lstm_persist,
                      hipFuncAttributeMaxDynamicSharedMemorySize, SMEM_BYTES);

  void* args[] = {(void*)&xb, (void*)&hseq, (void*)&wt_blk, (void*)&bias,
                  (void*)&out, (void*)&flags};
  hipLaunchCooperativeKernel((void*)lstm_persist, dim3(256), dim3(512), args,
                             SMEM_BYTES, stream);
}